// Round 16
// baseline (755.314 us; speedup 1.0000x reference)
//
#include <hip/hip_runtime.h>

#define NEGV (-1000000000.0f)

typedef __attribute__((ext_vector_type(8))) short sh8;
typedef __attribute__((ext_vector_type(4))) short sh4;
typedef __attribute__((ext_vector_type(8))) __bf16 bf16x8;
typedef __attribute__((ext_vector_type(4))) float f32x4;

__device__ __forceinline__ float b2f(unsigned short u) {
  unsigned v = ((unsigned)u) << 16;
  return __builtin_bit_cast(float, v);
}
__device__ __forceinline__ unsigned short f2b(float f) {
  unsigned x = __builtin_bit_cast(unsigned, f);
  unsigned r = (x + 0x7fffu + ((x >> 16) & 1u)) >> 16;
  return (unsigned short)r;
}
__device__ __forceinline__ void g2l16(const void* g, void* l) {
  __builtin_amdgcn_global_load_lds((const __attribute__((address_space(1))) unsigned int*)g,
                                   (__attribute__((address_space(3))) unsigned int*)l, 16, 0, 0);
}
__device__ __forceinline__ f32x4 mfma16(bf16x8 a, bf16x8 b, f32x4 c) {
  return __builtin_amdgcn_mfma_f32_16x16x32_bf16(a, b, c, 0, 0, 0);
}
__device__ __forceinline__ float fast_tanh(float x) {
  x = fminf(fmaxf(x, -15.f), 15.f);
  float e = __expf(2.f * x);
  return (e - 1.f) / (e + 1.f);
}

// ---------------- fused prep: elementwise cvt (seq+his) + 5 weight transposes ----------------
__global__ __launch_bounds__(256)
void prep(const float* __restrict__ seq, unsigned short* __restrict__ seqb, int n4a,
          const float* __restrict__ his, unsigned short* __restrict__ hisb, int n4b,
          const float* __restrict__ s0, const float* __restrict__ s1,
          const float* __restrict__ s2, const float* __restrict__ s3,
          const float* __restrict__ s4,
          unsigned short* __restrict__ d0, unsigned short* __restrict__ d1,
          unsigned short* __restrict__ d2, unsigned short* __restrict__ d3,
          unsigned short* __restrict__ d4)
{
  const int t = threadIdx.x;
  if (blockIdx.x < 2048) {
    const int stride = 2048 * 256;
    for (int i = blockIdx.x * 256 + t; i < n4a; i += stride) {
      float4 v = ((const float4*)seq)[i];
      sh4 o;
      o[0] = (short)f2b(v.x); o[1] = (short)f2b(v.y);
      o[2] = (short)f2b(v.z); o[3] = (short)f2b(v.w);
      ((sh4*)seqb)[i] = o;
    }
    for (int i = blockIdx.x * 256 + t; i < n4b; i += stride) {
      float4 v = ((const float4*)his)[i];
      sh4 o;
      o[0] = (short)f2b(v.x); o[1] = (short)f2b(v.y);
      o[2] = (short)f2b(v.z); o[3] = (short)f2b(v.w);
      ((sh4*)hisb)[i] = o;
    }
    return;
  }
  __shared__ float tile[64][65];
  int z2 = blockIdx.x - 2048;
  int zz = z2 >> 8, rem = z2 & 255;
  int by = rem >> 4, bx = rem & 15;
  const float* src; unsigned short* dst;
  switch (zz) {
    case 0: src = s0; dst = d0; break;
    case 1: src = s1; dst = d1; break;
    case 2: src = s2; dst = d2; break;
    case 3: src = s3; dst = d3; break;
    default: src = s4; dst = d4; break;
  }
  int tx = t & 63, ty = t >> 6;
#pragma unroll
  for (int i = 0; i < 16; ++i) {
    int r = i * 4 + ty;
    tile[r][tx] = src[(size_t)(by * 64 + r) * 1024 + bx * 64 + tx];
  }
  __syncthreads();
#pragma unroll
  for (int i = 0; i < 16; ++i) {
    int r = i * 4 + ty;
    dst[(size_t)(bx * 64 + r) * 1024 + by * 64 + tx] = f2b(tile[tx][r]);
  }
}

// ---------------- 128x128 bf16 GEMM, BK=64, single-buffer 32KB, 4 blocks/CU ----------------
template<int EPI>
__global__ __launch_bounds__(256, 4)
void gemm128b64(const unsigned short* __restrict__ A, const unsigned short* __restrict__ Bt,
                int nbx,
                const float* __restrict__ b0, const float* __restrict__ b1,
                const float* __restrict__ b2,
                unsigned short* __restrict__ O0, unsigned short* __restrict__ O1,
                unsigned short* __restrict__ O2)
{
  __shared__ unsigned short ldsA[8192];  // 128 rows x 64 k, row 128B
  __shared__ unsigned short ldsB[8192];
  const int tid = threadIdx.x;
  const int w = tid >> 6, l = tid & 63;
  const int wr = w >> 1, wc = w & 1;
  const int lr = l & 15, g = l >> 4;

  const int wg = blockIdx.x;
  const int cpx = gridDim.x >> 3;
  const int wgid = (wg & 7) * cpx + (wg >> 3);
  const int bx = wgid % nbx, by = wgid / nbx;
  const size_t m0 = (size_t)by * 128;
  const int n0 = bx * 128;

  f32x4 acc[4][4] = {};

  const int srow = tid >> 3;
  const int sk = ((tid & 7) ^ ((tid >> 3) & 7)) * 8;
  const unsigned short* gA = A + (m0 + srow) * 1024 + sk;
  const unsigned short* gB = Bt + ((size_t)n0 + srow) * 1024 + sk;
  const int ldst = w * 1024;

  const int chs = lr & 7;
  const int ck0 = ((0 * 4 + g) ^ chs) * 16;
  const int ck1 = ((1 * 4 + g) ^ chs) * 16;
  const int aRd = (wr * 64 + lr) * 128;
  const int bRd = (wc * 64 + lr) * 128;

#define STG64(KT)                                                        \
  { const int ko_ = (KT) * 64;                                           \
    g2l16(gA + ko_,             (char*)ldsA + ldst);                     \
    g2l16(gA + 32 * 1024 + ko_, (char*)ldsA + 4096 + ldst);              \
    g2l16(gA + 64 * 1024 + ko_, (char*)ldsA + 8192 + ldst);              \
    g2l16(gA + 96 * 1024 + ko_, (char*)ldsA + 12288 + ldst);             \
    g2l16(gB + ko_,             (char*)ldsB + ldst);                     \
    g2l16(gB + 32 * 1024 + ko_, (char*)ldsB + 4096 + ldst);              \
    g2l16(gB + 64 * 1024 + ko_, (char*)ldsB + 8192 + ldst);              \
    g2l16(gB + 96 * 1024 + ko_, (char*)ldsB + 12288 + ldst); }

  STG64(0)
#pragma unroll 1
  for (int kt = 0; kt < 16; ++kt) {
    __syncthreads();
    bf16x8 af[4], bf[4];
#pragma unroll
    for (int i = 0; i < 4; ++i)
      af[i] = *(const bf16x8*)((const char*)ldsA + aRd + i * 2048 + ck0);
#pragma unroll
    for (int j = 0; j < 4; ++j)
      bf[j] = *(const bf16x8*)((const char*)ldsB + bRd + j * 2048 + ck0);
#pragma unroll
    for (int i = 0; i < 4; ++i)
#pragma unroll
      for (int j = 0; j < 4; ++j)
        acc[i][j] = mfma16(af[i], bf[j], acc[i][j]);
#pragma unroll
    for (int i = 0; i < 4; ++i)
      af[i] = *(const bf16x8*)((const char*)ldsA + aRd + i * 2048 + ck1);
#pragma unroll
    for (int j = 0; j < 4; ++j)
      bf[j] = *(const bf16x8*)((const char*)ldsB + bRd + j * 2048 + ck1);
#pragma unroll
    for (int i = 0; i < 4; ++i)
#pragma unroll
      for (int j = 0; j < 4; ++j)
        acc[i][j] = mfma16(af[i], bf[j], acc[i][j]);
    __syncthreads();
    if (kt < 15) STG64(kt + 1)
  }
#undef STG64

  if (EPI == 0) {
#pragma unroll
    for (int j = 0; j < 4; ++j) {
      int col = n0 + wc * 64 + j * 16 + lr;
      float bv = b0[col];
#pragma unroll
      for (int i = 0; i < 4; ++i) {
        size_t rowb = m0 + wr * 64 + i * 16 + g * 4;
#pragma unroll
        for (int r = 0; r < 4; ++r)
          O0[(rowb + r) * 1024 + col] = f2b(acc[i][j][r] + bv);
      }
    }
  } else {
#pragma unroll
    for (int j = 0; j < 4; ++j) {
      int col3 = n0 + wc * 64 + j * 16 + lr;
      int part = col3 >> 10, c = col3 & 1023;
      float bv = (part == 0) ? b0[c] : (part == 1) ? b1[c] : b2[c];
      if (part < 2) {
        unsigned short* O = part == 0 ? O0 : O1;
#pragma unroll
        for (int i = 0; i < 4; ++i) {
          size_t rowb = m0 + wr * 64 + i * 16 + g * 4;
#pragma unroll
          for (int r = 0; r < 4; ++r)
            O[(rowb + r) * 1024 + c] = f2b(acc[i][j][r] + bv);
        }
      } else {  // v -> transposed vT[(b*4+h)*256 + d][512]
        int h = c >> 8, d = c & 255;
#pragma unroll
        for (int i = 0; i < 4; ++i) {
          size_t row = m0 + wr * 64 + i * 16 + g * 4;
          int bb = (int)(row >> 9), ll = (int)(row & 511);
          size_t base = ((size_t)(bb * 4 + h) * 256 + d) * 512 + ll;
#pragma unroll
          for (int r = 0; r < 4; ++r)
            O2[base + r] = f2b(acc[i][j][r] + bv);
        }
      }
    }
  }
}

// ---------------- 256x128 bf16 GEMM, BK=64, 8x4 wave tile (his-score only) ----------------
// LDS-read-traffic experiment: wave tile 128x64 (8x4 MFMAs) -> 12 ds_read per
// 32 MFMAs (23 B/kFLOP vs 32 for 4x4). LDS 48KB, ~2 blocks/CU (VGPR-capped);
// LDS throughput is per-CU so reuse gain should outweigh occupancy loss.
// Same verified swizzle and 2-barrier structure as gemm128b64.
__global__ __launch_bounds__(256, 2)
void gemm256x128(const unsigned short* __restrict__ A, const unsigned short* __restrict__ Bt,
                 int nbx, const float* __restrict__ aq, const float* __restrict__ wa,
                 float* __restrict__ sc)
{
  __shared__ unsigned short ldsA[16384];  // 256 rows x 64 k, row 128B
  __shared__ unsigned short ldsB[8192];   // 128 rows x 64 k
  const int tid = threadIdx.x;
  const int w = tid >> 6, l = tid & 63;
  const int wm = w >> 1, wn = w & 1;
  const int lr = l & 15, g = l >> 4;

  const int wg = blockIdx.x;
  const int cpx = gridDim.x >> 3;
  const int wgid = (wg & 7) * cpx + (wg >> 3);
  const int bx = wgid % nbx, by = wgid / nbx;
  const size_t m0 = (size_t)by * 256;
  const int n0 = bx * 128;

  f32x4 acc[8][4] = {};

  const int srow = tid >> 3;
  const int sk = ((tid & 7) ^ ((tid >> 3) & 7)) * 8;
  const unsigned short* gA = A + (m0 + srow) * 1024 + sk;
  const unsigned short* gB = Bt + ((size_t)n0 + srow) * 1024 + sk;
  const int ldst = w * 1024;

  const int chs = lr & 7;
  const int ck0 = ((0 * 4 + g) ^ chs) * 16;
  const int ck1 = ((1 * 4 + g) ^ chs) * 16;
  const int aRd = (wm * 128 + lr) * 128;  // + i*2048 + ck, i in [0,8)
  const int bRd = (wn * 64 + lr) * 128;   // + j*2048 + ck

#define STGX(KT)                                                         \
  { const int ko_ = (KT) * 64;                                           \
    g2l16(gA + ko_,              (char*)ldsA + ldst);                    \
    g2l16(gA + 32 * 1024 + ko_,  (char*)ldsA + 4096 + ldst);             \
    g2l16(gA + 64 * 1024 + ko_,  (char*)ldsA + 8192 + ldst);             \
    g2l16(gA + 96 * 1024 + ko_,  (char*)ldsA + 12288 + ldst);            \
    g2l16(gA + 128 * 1024 + ko_, (char*)ldsA + 16384 + ldst);            \
    g2l16(gA + 160 * 1024 + ko_, (char*)ldsA + 20480 + ldst);            \
    g2l16(gA + 192 * 1024 + ko_, (char*)ldsA + 24576 + ldst);            \
    g2l16(gA + 224 * 1024 + ko_, (char*)ldsA + 28672 + ldst);            \
    g2l16(gB + ko_,              (char*)ldsB + ldst);                    \
    g2l16(gB + 32 * 1024 + ko_,  (char*)ldsB + 4096 + ldst);             \
    g2l16(gB + 64 * 1024 + ko_,  (char*)ldsB + 8192 + ldst);             \
    g2l16(gB + 96 * 1024 + ko_,  (char*)ldsB + 12288 + ldst); }

  STGX(0)
#pragma unroll 1
  for (int kt = 0; kt < 16; ++kt) {
    __syncthreads();   // drains vmcnt: tile kt resident
    bf16x8 af[8], bf[4];
#pragma unroll
    for (int i = 0; i < 8; ++i)
      af[i] = *(const bf16x8*)((const char*)ldsA + aRd + i * 2048 + ck0);
#pragma unroll
    for (int j = 0; j < 4; ++j)
      bf[j] = *(const bf16x8*)((const char*)ldsB + bRd + j * 2048 + ck0);
#pragma unroll
    for (int i = 0; i < 8; ++i)
#pragma unroll
      for (int j = 0; j < 4; ++j)
        acc[i][j] = mfma16(af[i], bf[j], acc[i][j]);
#pragma unroll
    for (int i = 0; i < 8; ++i)
      af[i] = *(const bf16x8*)((const char*)ldsA + aRd + i * 2048 + ck1);
#pragma unroll
    for (int j = 0; j < 4; ++j)
      bf[j] = *(const bf16x8*)((const char*)ldsB + bRd + j * 2048 + ck1);
#pragma unroll
    for (int i = 0; i < 8; ++i)
#pragma unroll
      for (int j = 0; j < 4; ++j)
        acc[i][j] = mfma16(af[i], bf[j], acc[i][j]);
    __syncthreads();   // all reads done before overwrite
    if (kt < 15) STGX(kt + 1)
  }
#undef STGX

  // his-score epilogue: row = m0 + wm*128 + i*16 + g*4 + r; col = n0 + wn*64 + j*16 + lr
  const int bb = (int)(m0 >> 11);  // 2048 % 256 == 0 -> whole tile in one batch
#pragma unroll
  for (int i = 0; i < 8; ++i) {
    float rp[4] = {0.f, 0.f, 0.f, 0.f};
#pragma unroll
    for (int j = 0; j < 4; ++j) {
      int col = n0 + wn * 64 + j * 16 + lr;
      float wav = wa[col];
      float aqv = aq[bb * 1024 + col];
#pragma unroll
      for (int r = 0; r < 4; ++r)
        rp[r] += wav * fast_tanh(acc[i][j][r] + aqv);
    }
#pragma unroll
    for (int off = 1; off < 16; off <<= 1)
#pragma unroll
      for (int r = 0; r < 4; ++r)
        rp[r] += __shfl_xor(rp[r], off, 64);
    if (lr == 0) {
      size_t rowb = m0 + wm * 128 + i * 16 + g * 4;
#pragma unroll
      for (int r = 0; r < 4; ++r)
        atomicAdd(&sc[rowb + r], rp[r]);
    }
  }
}

// ---------------- fused attention, QBLK=64 (round-15 proven) ----------------
__global__ __launch_bounds__(256, 2)
void attn_kernel(const unsigned short* __restrict__ q, const unsigned short* __restrict__ k,
                 const unsigned short* __restrict__ vT, const float* __restrict__ seq_mask,
                 unsigned short* __restrict__ ctx, float* __restrict__ attn_out)
{
  __shared__ char smem[68608];
  unsigned short* Qs = (unsigned short*)smem;           // [64][264]
  unsigned short* Ps = (unsigned short*)smem;           // [64][520]
  float* redm = (float*)(smem + 66560);
  float* reds = (float*)(smem + 67584);
  const int t = threadIdx.x, w = t >> 6, l = t & 63;
  const int lr = l & 15, g = l >> 4, lk8 = g * 8;
  const int wg = blockIdx.x;
  const int wgid = (wg & 7) * 128 + (wg >> 3);
  const int qt = wgid & 7, bh = wgid >> 3;
  const int h = bh & 3, b = bh >> 2;
  const int l0 = qt * 64;

  for (int idx = t; idx < 64 * 32; idx += 256) {
    int r = idx >> 5, ch = (idx & 31) * 8;
    *(sh8*)&Qs[r * 264 + ch] =
        *(const sh8*)&q[((size_t)(b * 512 + l0 + r)) * 1024 + h * 256 + ch];
  }
  __syncthreads();

  f32x4 accs[4][8] = {};
  const unsigned short* kbase = k + ((size_t)b * 512) * 1024 + h * 256;
#pragma unroll
  for (int ds = 0; ds < 8; ++ds) {
    int d0 = ds * 32;
    bf16x8 a[4];
#pragma unroll
    for (int i = 0; i < 4; ++i)
      a[i] = *(const bf16x8*)&Qs[(i * 16 + lr) * 264 + d0 + lk8];
#pragma unroll
    for (int j = 0; j < 8; ++j) {
      int kj = w * 128 + j * 16 + lr;
      bf16x8 bb = *(const bf16x8*)&kbase[(size_t)kj * 1024 + d0 + lk8];
#pragma unroll
      for (int i = 0; i < 4; ++i)
        accs[i][j] = mfma16(a[i], bb, accs[i][j]);
    }
  }

#pragma unroll
  for (int j = 0; j < 8; ++j) {
    int col = w * 128 + j * 16 + lr;
    float mv = seq_mask[b * 512 + col];
    bool msk = (mv == 0.f);
#pragma unroll
    for (int i = 0; i < 4; ++i)
#pragma unroll
      for (int r = 0; r < 4; ++r)
        accs[i][j][r] = msk ? NEGV : accs[i][j][r] * 0.0625f;
  }

  float mx[4][4], sm[4][4];
#pragma unroll
  for (int i = 0; i < 4; ++i)
#pragma unroll
    for (int r = 0; r < 4; ++r) {
      float m = accs[i][0][r];
#pragma unroll
      for (int j = 1; j < 8; ++j) m = fmaxf(m, accs[i][j][r]);
      mx[i][r] = m;
    }
#pragma unroll
  for (int off = 1; off < 16; off <<= 1)
#pragma unroll
    for (int i = 0; i < 4; ++i)
#pragma unroll
      for (int r = 0; r < 4; ++r)
        mx[i][r] = fmaxf(mx[i][r], __shfl_xor(mx[i][r], off, 64));
  if (lr == 0) {
#pragma unroll
    for (int i = 0; i < 4; ++i)
#pragma unroll
      for (int r = 0; r < 4; ++r)
        redm[w * 64 + i * 16 + g * 4 + r] = mx[i][r];
  }
  __syncthreads();
#pragma unroll
  for (int i = 0; i < 4; ++i)
#pragma unroll
    for (int r = 0; r < 4; ++r) {
      int row = i * 16 + g * 4 + r;
      mx[i][r] = fmaxf(fmaxf(redm[row], redm[64 + row]),
                       fmaxf(redm[128 + row], redm[192 + row]));
      sm[i][r] = 0.f;
    }

#pragma unroll
  for (int i = 0; i < 4; ++i)
#pragma unroll
    for (int j = 0; j < 8; ++j)
#pragma unroll
      for (int r = 0; r < 4; ++r) {
        float p = __expf(accs[i][j][r] - mx[i][r]);
        accs[i][j][r] = p;
        sm[i][r] += p;
      }
#pragma unroll
  for (int off = 1; off < 16; off <<= 1)
#pragma unroll
    for (int i = 0; i < 4; ++i)
#pragma unroll
      for (int r = 0; r < 4; ++r)
        sm[i][r] += __shfl_xor(sm[i][r], off, 64);
  if (lr == 0) {
#pragma unroll
    for (int i = 0; i < 4; ++i)
#pragma unroll
      for (int r = 0; r < 4; ++r)
        reds[w * 64 + i * 16 + g * 4 + r] = sm[i][r];
  }
  __syncthreads();
#pragma unroll
  for (int i = 0; i < 4; ++i)
#pragma unroll
    for (int r = 0; r < 4; ++r) {
      int row = i * 16 + g * 4 + r;
      float s = reds[row] + reds[64 + row] + reds[128 + row] + reds[192 + row];
      sm[i][r] = 1.f / s;
    }

#pragma unroll
  for (int i = 0; i < 4; ++i)
#pragma unroll
    for (int j = 0; j < 8; ++j) {
      int col = w * 128 + j * 16 + lr;
#pragma unroll
      for (int r = 0; r < 4; ++r) {
        int row = i * 16 + g * 4 + r;
        float pn = accs[i][j][r] * sm[i][r];
        Ps[row * 520 + col] = f2b(pn);
        if (h == 0)
          attn_out[((size_t)(b * 512 + l0 + row)) * 512 + col] = pn;
      }
    }
  __syncthreads();

  f32x4 acco[4][4] = {};
  const unsigned short* vbase = vT + ((size_t)(b * 4 + h)) * 256 * 512;
#pragma unroll
  for (int ks = 0; ks < 16; ++ks) {
    int kj0 = ks * 32;
    bf16x8 a[4];
#pragma unroll
    for (int i = 0; i < 4; ++i)
      a[i] = *(const bf16x8*)&Ps[(i * 16 + lr) * 520 + kj0 + lk8];
#pragma unroll
    for (int j = 0; j < 4; ++j) {
      int d = w * 64 + j * 16 + lr;
      bf16x8 bb = *(const bf16x8*)&vbase[(size_t)d * 512 + kj0 + lk8];
#pragma unroll
      for (int i = 0; i < 4; ++i)
        acco[i][j] = mfma16(a[i], bb, acco[i][j]);
    }
  }
#pragma unroll
  for (int i = 0; i < 4; ++i)
#pragma unroll
    for (int j = 0; j < 4; ++j) {
      int col = w * 64 + j * 16 + lr;
#pragma unroll
      for (int r = 0; r < 4; ++r) {
        int row = i * 16 + g * 4 + r;
        ctx[((size_t)(b * 512 + l0 + row)) * 1024 + h * 256 + col] = f2b(acco[i][j][r]);
      }
    }
}

// ---------------- LN + masked mean over L ----------------
__global__ __launch_bounds__(256)
void ln_mean(const unsigned short* __restrict__ sa, const float* __restrict__ g,
             const float* __restrict__ bt, const float* __restrict__ mask,
             float* __restrict__ poi_sum)
{
  const int b = blockIdx.y, ch = blockIdx.x;
  const int t = threadIdx.x, w = t >> 6, l = t & 63;
  float gg[16], bb[16];
#pragma unroll
  for (int j = 0; j < 16; ++j) { gg[j] = g[l * 16 + j]; bb[j] = bt[l * 16 + j]; }
  float accv[16];
#pragma unroll
  for (int j = 0; j < 16; ++j) accv[j] = 0.f;
  for (int rr = 0; rr < 16; ++rr) {
    int row = ch * 64 + w * 16 + rr;
    const unsigned short* rp = sa + ((size_t)(b * 512 + row)) * 1024 + l * 16;
    float x[16];
    sh8 v0 = *(const sh8*)rp;
    sh8 v1 = *(const sh8*)(rp + 8);
#pragma unroll
    for (int j = 0; j < 8; ++j) {
      x[j] = b2f((unsigned short)v0[j]);
      x[8 + j] = b2f((unsigned short)v1[j]);
    }
    float s = 0.f, s2 = 0.f;
#pragma unroll
    for (int j = 0; j < 16; ++j) { s += x[j]; s2 += x[j] * x[j]; }
#pragma unroll
    for (int off = 1; off < 64; off <<= 1) {
      s += __shfl_xor(s, off, 64);
      s2 += __shfl_xor(s2, off, 64);
    }
    float mean = s * (1.f / 1024.f);
    float var = s2 * (1.f / 1024.f) - mean * mean;
    float rinv = rsqrtf(var + 1e-5f);
    float mk = mask[b * 512 + row];
#pragma unroll
    for (int j = 0; j < 16; ++j) accv[j] += ((x[j] - mean) * rinv * gg[j] + bb[j]) * mk;
  }
#pragma unroll
  for (int j = 0; j < 16; ++j) atomicAdd(&poi_sum[b * 1024 + l * 16 + j], accv[j]);
}

// poi[b][n] = ps[b][n]/512;  aq[b][n] = (1/512) * sum_d ps[b][d] * wq[d][n]
__global__ __launch_bounds__(256)
void poi_gemv(const float* __restrict__ ps, const float* __restrict__ wq,
              float* __restrict__ poi, float* __restrict__ aq)
{
  const int b = blockIdx.y;
  const int n = blockIdx.x * 256 + threadIdx.x;
  const float* ib = ps + b * 1024;
  float acc = 0.f;
  for (int d = 0; d < 1024; d += 4) {
    acc += ib[d]     * wq[(size_t)d * 1024 + n]
         + ib[d + 1] * wq[(size_t)(d + 1) * 1024 + n]
         + ib[d + 2] * wq[(size_t)(d + 2) * 1024 + n]
         + ib[d + 3] * wq[(size_t)(d + 3) * 1024 + n];
  }
  poi[b * 1024 + n] = ib[n] * (1.f / 512.f);
  aq[b * 1024 + n] = acc * (1.f / 512.f);
}

// ---------------- fused his-softmax + weighted row-sum ----------------
__global__ __launch_bounds__(256)
void softhw(const float* __restrict__ sc, const float* __restrict__ mask,
            const unsigned short* __restrict__ his, float* __restrict__ hw)
{
  __shared__ float wloc[2048];
  __shared__ float red[4];
  const int b = blockIdx.y, kc = blockIdx.x;
  const int t = threadIdx.x, w = t >> 6, l = t & 63;
  float v[8];
  float mx = -3.0e38f;
#pragma unroll
  for (int i = 0; i < 8; ++i) {
    int kk = t + i * 256;
    float s = (mask[b * 2048 + kk] == 0.f) ? NEGV : sc[b * 2048 + kk];
    v[i] = s;
    mx = fmaxf(mx, s);
  }
#pragma unroll
  for (int off = 1; off < 64; off <<= 1) mx = fmaxf(mx, __shfl_xor(mx, off, 64));
  if (l == 0) red[w] = mx;
  __syncthreads();
  mx = fmaxf(fmaxf(red[0], red[1]), fmaxf(red[2], red[3]));
  float sum = 0.f;
#pragma unroll
  for (int i = 0; i < 8; ++i) {
    v[i] = __expf(v[i] - mx);
    wloc[t + i * 256] = v[i];
    sum += v[i];
  }
#pragma unroll
  for (int off = 1; off < 64; off <<= 1) sum += __shfl_xor(sum, off, 64);
  __syncthreads();
  if (l == 0) red[w] = sum;
  __syncthreads();
  sum = red[0] + red[1] + red[2] + red[3];
  const float inv = 1.f / sum;

  const int cb = t * 4;
  float a0 = 0.f, a1 = 0.f, a2 = 0.f, a3 = 0.f;
  for (int kk = 0; kk < 256; ++kk) {
    int k = kc * 256 + kk;
    float wg = wloc[k] * inv;
    sh4 vv = *(const sh4*)&his[((size_t)(b * 2048 + k)) * 1024 + cb];
    a0 += wg * b2f((unsigned short)vv[0]);
    a1 += wg * b2f((unsigned short)vv[1]);
    a2 += wg * b2f((unsigned short)vv[2]);
    a3 += wg * b2f((unsigned short)vv[3]);
  }
  atomicAdd(&hw[b * 1024 + cb + 0], a0);
  atomicAdd(&hw[b * 1024 + cb + 1], a1);
  atomicAdd(&hw[b * 1024 + cb + 2], a2);
  atomicAdd(&hw[b * 1024 + cb + 3], a3);
}

__global__ __launch_bounds__(256)
void gemv32(const float* __restrict__ in, const float* __restrict__ W, float* __restrict__ out)
{
  const int b = blockIdx.y;
  const int n = blockIdx.x * 256 + threadIdx.x;
  const float* ib = in + b * 1024;
  float acc = 0.f;
  for (int d = 0; d < 1024; d += 4) {
    acc += ib[d]     * W[(size_t)d * 1024 + n]
         + ib[d + 1] * W[(size_t)(d + 1) * 1024 + n]
         + ib[d + 2] * W[(size_t)(d + 2) * 1024 + n]
         + ib[d + 3] * W[(size_t)(d + 3) * 1024 + n];
  }
  out[b * 1024 + n] = acc;
}

__global__ __launch_bounds__(256)
void final_kernel(const float* __restrict__ aa_out, const float* __restrict__ g,
                  const float* __restrict__ bt, const float* __restrict__ poi,
                  float* __restrict__ out)
{
  __shared__ float r1[4], r2[4];
  const int b = blockIdx.x, t = threadIdx.x, w = t >> 6, l = t & 63;
  float x[4];
#pragma unroll
  for (int j = 0; j < 4; ++j) x[j] = aa_out[b * 1024 + t * 4 + j];
  float s = 0.f, s2 = 0.f;
#pragma unroll
  for (int j = 0; j < 4; ++j) { s += x[j]; s2 += x[j] * x[j]; }
#pragma unroll
  for (int off = 1; off < 64; off <<= 1) {
    s += __shfl_xor(s, off, 64);
    s2 += __shfl_xor(s2, off, 64);
  }
  if (l == 0) { r1[w] = s; r2[w] = s2; }
  __syncthreads();
  s = r1[0] + r1[1] + r1[2] + r1[3];
  s2 = r2[0] + r2[1] + r2[2] + r2[3];
  float mean = s * (1.f / 1024.f);
  float var = s2 * (1.f / 1024.f) - mean * mean;
  float rinv = rsqrtf(var + 1e-5f);
#pragma unroll
  for (int j = 0; j < 4; ++j) {
    int c = t * 4 + j;
    float lnv = (x[j] - mean) * rinv * g[c] + bt[c];
    float pv = poi[b * 1024 + c];
    out[b * 2048 + c] = pv;
    out[b * 2048 + 1024 + c] = pv + lnv;
  }
}

// ---------------- host launch ----------------
extern "C" void kernel_launch(void* const* d_in, const int* in_sizes, int n_in,
                              void* d_out, int out_size, void* d_ws, size_t ws_size,
                              hipStream_t stream)
{
  const float* seq_emb  = (const float*)d_in[0];
  const float* seq_mask = (const float*)d_in[1];
  const float* his_emb  = (const float*)d_in[2];
  const float* his_mask = (const float*)d_in[3];
  const float* sa_wq = (const float*)d_in[4];
  const float* sa_bq = (const float*)d_in[5];
  const float* sa_wk = (const float*)d_in[6];
  const float* sa_bk = (const float*)d_in[7];
  const float* sa_wv = (const float*)d_in[8];
  const float* sa_bv = (const float*)d_in[9];
  const float* sa_wo = (const float*)d_in[10];
  const float* sa_bo = (const float*)d_in[11];
  const float* sn_g  = (const float*)d_in[12];
  const float* sn_b  = (const float*)d_in[13];
  const float* aa_wq = (const float*)d_in[14];
  const float* aa_wk = (const float*)d_in[15];
  const float* aa_wv = (const float*)d_in[16];
  const float* aa_wo = (const float*)d_in[17];
  const float* aa_wa = (const float*)d_in[18];
  const float* ln_g  = (const float*)d_in[19];
  const float* ln_b  = (const float*)d_in[20];
  float* out = (float*)d_out;

  char* p = (char*)d_ws;
  size_t off = 0;
  auto alloc = [&](size_t bytes) -> void* {
    void* r = p + off;
    off += (bytes + 255) & ~(size_t)255;
    return r;
  };
  unsigned short* seqb = (unsigned short*)alloc((size_t)16384 * 1024 * 2);
  unsigned short* hisb = (unsigned short*)alloc((size_t)65536 * 1024 * 2);
  unsigned short* wcat = (unsigned short*)alloc((size_t)3072 * 1024 * 2);
  unsigned short* woT  = (unsigned short*)alloc((size_t)1024 * 1024 * 2);
  unsigned short* awkT = (unsigned short*)alloc((size_t)1024 * 1024 * 2);
  unsigned short* qb   = (unsigned short*)alloc((size_t)16384 * 1024 * 2);
  unsigned short* kb   = (unsigned short*)alloc((size_t)16384 * 1024 * 2);
  unsigned short* vTb  = (unsigned short*)alloc((size_t)16384 * 1024 * 2);
  unsigned short* ctxb = (unsigned short*)alloc((size_t)16384 * 1024 * 2);
  unsigned short* saob = (unsigned short*)alloc((size_t)16384 * 1024 * 2);
  float* poi_sum = (float*)alloc((size_t)32 * 1024 * 4);
  float* poi     = (float*)alloc((size_t)32 * 1024 * 4);
  float* aqb     = (float*)alloc((size_t)32 * 1024 * 4);
  float* ascore  = (float*)alloc((size_t)32 * 2048 * 4);
  float* hwb     = (float*)alloc((size_t)32 * 1024 * 4);
  float* actx    = (float*)alloc((size_t)32 * 1024 * 4);
  float* aaout   = (float*)alloc((size_t)32 * 1024 * 4);
  if (off > ws_size) return;

  hipMemsetAsync(poi_sum, 0, (size_t)(6 * 32 * 1024) * 4, stream);

  prep<<<3328, 256, 0, stream>>>(seq_emb, seqb, 16384 * 1024 / 4,
                                 his_emb, hisb, 65536 * 1024 / 4,
                                 sa_wq, sa_wk, sa_wv, sa_wo, aa_wk,
                                 wcat, wcat + (size_t)1024 * 1024,
                                 wcat + (size_t)2048 * 1024, woT, awkT);

  // fused QKV: M=16384, N=3072 -> 128 x 24 = 3072 blocks
  gemm128b64<1><<<3072, 256, 0, stream>>>(seqb, wcat, 24, sa_bq, sa_bk, sa_bv,
                                          qb, kb, vTb);

  // attention: QBLK=64 -> 1024 blocks
  attn_kernel<<<1024, 256, 0, stream>>>(qb, kb, vTb, seq_mask, ctxb, out + 65536);

  // sa_out: M=16384, N=1024 -> 1024 blocks
  gemm128b64<0><<<1024, 256, 0, stream>>>(ctxb, woT, 8, sa_bo, nullptr, nullptr,
                                          saob, nullptr, nullptr);
  ln_mean<<<dim3(8, 32), 256, 0, stream>>>(saob, sn_g, sn_b, seq_mask, poi_sum);
  poi_gemv<<<dim3(4, 32), 256, 0, stream>>>(poi_sum, aa_wq, poi, aqb);

  // his scores: M=65536 (256-tiles) x N=1024 (128-tiles) -> 256 x 8 = 2048 blocks
  gemm256x128<<<2048, 256, 0, stream>>>(hisb, awkT, 8, aqb, aa_wa, ascore);
  softhw<<<dim3(8, 32), 256, 0, stream>>>(ascore, his_mask, hisb, hwb);
  gemv32<<<dim3(4, 32), 256, 0, stream>>>(hwb, aa_wv, actx);
  gemv32<<<dim3(4, 32), 256, 0, stream>>>(actx, aa_wo, aaout);
  final_kernel<<<32, 256, 0, stream>>>(aaout, ln_g, ln_b, poi, out);
}

// Round 17
// 739.346 us; speedup vs baseline: 1.0216x; 1.0216x over previous
//
#include <hip/hip_runtime.h>

#define NEGV (-1000000000.0f)

typedef __attribute__((ext_vector_type(8))) short sh8;
typedef __attribute__((ext_vector_type(4))) short sh4;
typedef __attribute__((ext_vector_type(8))) __bf16 bf16x8;
typedef __attribute__((ext_vector_type(4))) float f32x4;

__device__ __forceinline__ float b2f(unsigned short u) {
  unsigned v = ((unsigned)u) << 16;
  return __builtin_bit_cast(float, v);
}
__device__ __forceinline__ unsigned short f2b(float f) {
  unsigned x = __builtin_bit_cast(unsigned, f);
  unsigned r = (x + 0x7fffu + ((x >> 16) & 1u)) >> 16;
  return (unsigned short)r;
}
__device__ __forceinline__ void g2l16(const void* g, void* l) {
  __builtin_amdgcn_global_load_lds((const __attribute__((address_space(1))) unsigned int*)g,
                                   (__attribute__((address_space(3))) unsigned int*)l, 16, 0, 0);
}
__device__ __forceinline__ f32x4 mfma16(bf16x8 a, bf16x8 b, f32x4 c) {
  return __builtin_amdgcn_mfma_f32_16x16x32_bf16(a, b, c, 0, 0, 0);
}
__device__ __forceinline__ float fast_tanh(float x) {
  x = fminf(fmaxf(x, -15.f), 15.f);
  float e = __expf(2.f * x);
  return (e - 1.f) / (e + 1.f);
}

// ---------------- fused prep: elementwise cvt (seq+his) + 5 weight transposes ----------------
__global__ __launch_bounds__(256)
void prep(const float* __restrict__ seq, unsigned short* __restrict__ seqb, int n4a,
          const float* __restrict__ his, unsigned short* __restrict__ hisb, int n4b,
          const float* __restrict__ s0, const float* __restrict__ s1,
          const float* __restrict__ s2, const float* __restrict__ s3,
          const float* __restrict__ s4,
          unsigned short* __restrict__ d0, unsigned short* __restrict__ d1,
          unsigned short* __restrict__ d2, unsigned short* __restrict__ d3,
          unsigned short* __restrict__ d4)
{
  const int t = threadIdx.x;
  if (blockIdx.x < 2048) {
    const int stride = 2048 * 256;
    for (int i = blockIdx.x * 256 + t; i < n4a; i += stride) {
      float4 v = ((const float4*)seq)[i];
      sh4 o;
      o[0] = (short)f2b(v.x); o[1] = (short)f2b(v.y);
      o[2] = (short)f2b(v.z); o[3] = (short)f2b(v.w);
      ((sh4*)seqb)[i] = o;
    }
    for (int i = blockIdx.x * 256 + t; i < n4b; i += stride) {
      float4 v = ((const float4*)his)[i];
      sh4 o;
      o[0] = (short)f2b(v.x); o[1] = (short)f2b(v.y);
      o[2] = (short)f2b(v.z); o[3] = (short)f2b(v.w);
      ((sh4*)hisb)[i] = o;
    }
    return;
  }
  __shared__ float tile[64][65];
  int z2 = blockIdx.x - 2048;
  int zz = z2 >> 8, rem = z2 & 255;
  int by = rem >> 4, bx = rem & 15;
  const float* src; unsigned short* dst;
  switch (zz) {
    case 0: src = s0; dst = d0; break;
    case 1: src = s1; dst = d1; break;
    case 2: src = s2; dst = d2; break;
    case 3: src = s3; dst = d3; break;
    default: src = s4; dst = d4; break;
  }
  int tx = t & 63, ty = t >> 6;
#pragma unroll
  for (int i = 0; i < 16; ++i) {
    int r = i * 4 + ty;
    tile[r][tx] = src[(size_t)(by * 64 + r) * 1024 + bx * 64 + tx];
  }
  __syncthreads();
#pragma unroll
  for (int i = 0; i < 16; ++i) {
    int r = i * 4 + ty;
    dst[(size_t)(bx * 64 + r) * 1024 + by * 64 + tx] = f2b(tile[tx][r]);
  }
}

// ---------------- 128x128 bf16 GEMM, BK=64, single-buffer 32KB, 4 blocks/CU ----------------
// Best measured structure (round 13/14): 808 TF on the his shape, 0 bank
// conflicts. Per iter: sync (drains vmcnt), {8 ds_read + 16 MFMA} x2, sync,
// stage next. Swizzle: phys chunk pc of row r holds global chunk pc^(r&7).
template<int EPI>
__global__ __launch_bounds__(256, 4)
void gemm128b64(const unsigned short* __restrict__ A, const unsigned short* __restrict__ Bt,
                int nbx,
                const float* __restrict__ b0, const float* __restrict__ b1,
                const float* __restrict__ b2,
                unsigned short* __restrict__ O0, unsigned short* __restrict__ O1,
                unsigned short* __restrict__ O2,
                const float* __restrict__ aq, const float* __restrict__ wa,
                float* __restrict__ sc)
{
  __shared__ unsigned short ldsA[8192];  // 128 rows x 64 k, row 128B
  __shared__ unsigned short ldsB[8192];
  const int tid = threadIdx.x;
  const int w = tid >> 6, l = tid & 63;
  const int wr = w >> 1, wc = w & 1;
  const int lr = l & 15, g = l >> 4;

  const int wg = blockIdx.x;
  const int cpx = gridDim.x >> 3;
  const int wgid = (wg & 7) * cpx + (wg >> 3);
  const int bx = wgid % nbx, by = wgid / nbx;
  const size_t m0 = (size_t)by * 128;
  const int n0 = bx * 128;

  f32x4 acc[4][4] = {};

  const int srow = tid >> 3;
  const int sk = ((tid & 7) ^ ((tid >> 3) & 7)) * 8;
  const unsigned short* gA = A + (m0 + srow) * 1024 + sk;
  const unsigned short* gB = Bt + ((size_t)n0 + srow) * 1024 + sk;
  const int ldst = w * 1024;

  const int chs = lr & 7;
  const int ck0 = ((0 * 4 + g) ^ chs) * 16;
  const int ck1 = ((1 * 4 + g) ^ chs) * 16;
  const int aRd = (wr * 64 + lr) * 128;
  const int bRd = (wc * 64 + lr) * 128;

#define STG64(KT)                                                        \
  { const int ko_ = (KT) * 64;                                           \
    g2l16(gA + ko_,             (char*)ldsA + ldst);                     \
    g2l16(gA + 32 * 1024 + ko_, (char*)ldsA + 4096 + ldst);              \
    g2l16(gA + 64 * 1024 + ko_, (char*)ldsA + 8192 + ldst);              \
    g2l16(gA + 96 * 1024 + ko_, (char*)ldsA + 12288 + ldst);             \
    g2l16(gB + ko_,             (char*)ldsB + ldst);                     \
    g2l16(gB + 32 * 1024 + ko_, (char*)ldsB + 4096 + ldst);              \
    g2l16(gB + 64 * 1024 + ko_, (char*)ldsB + 8192 + ldst);              \
    g2l16(gB + 96 * 1024 + ko_, (char*)ldsB + 12288 + ldst); }

  STG64(0)
#pragma unroll 1
  for (int kt = 0; kt < 16; ++kt) {
    __syncthreads();
    bf16x8 af[4], bf[4];
#pragma unroll
    for (int i = 0; i < 4; ++i)
      af[i] = *(const bf16x8*)((const char*)ldsA + aRd + i * 2048 + ck0);
#pragma unroll
    for (int j = 0; j < 4; ++j)
      bf[j] = *(const bf16x8*)((const char*)ldsB + bRd + j * 2048 + ck0);
#pragma unroll
    for (int i = 0; i < 4; ++i)
#pragma unroll
      for (int j = 0; j < 4; ++j)
        acc[i][j] = mfma16(af[i], bf[j], acc[i][j]);
#pragma unroll
    for (int i = 0; i < 4; ++i)
      af[i] = *(const bf16x8*)((const char*)ldsA + aRd + i * 2048 + ck1);
#pragma unroll
    for (int j = 0; j < 4; ++j)
      bf[j] = *(const bf16x8*)((const char*)ldsB + bRd + j * 2048 + ck1);
#pragma unroll
    for (int i = 0; i < 4; ++i)
#pragma unroll
      for (int j = 0; j < 4; ++j)
        acc[i][j] = mfma16(af[i], bf[j], acc[i][j]);
    __syncthreads();
    if (kt < 15) STG64(kt + 1)
  }
#undef STG64

  if (EPI == 0) {
#pragma unroll
    for (int j = 0; j < 4; ++j) {
      int col = n0 + wc * 64 + j * 16 + lr;
      float bv = b0[col];
#pragma unroll
      for (int i = 0; i < 4; ++i) {
        size_t rowb = m0 + wr * 64 + i * 16 + g * 4;
#pragma unroll
        for (int r = 0; r < 4; ++r)
          O0[(rowb + r) * 1024 + col] = f2b(acc[i][j][r] + bv);
      }
    }
  } else if (EPI == 1) {
#pragma unroll
    for (int j = 0; j < 4; ++j) {
      int col3 = n0 + wc * 64 + j * 16 + lr;
      int part = col3 >> 10, c = col3 & 1023;
      float bv = (part == 0) ? b0[c] : (part == 1) ? b1[c] : b2[c];
      if (part < 2) {
        unsigned short* O = part == 0 ? O0 : O1;
#pragma unroll
        for (int i = 0; i < 4; ++i) {
          size_t rowb = m0 + wr * 64 + i * 16 + g * 4;
#pragma unroll
          for (int r = 0; r < 4; ++r)
            O[(rowb + r) * 1024 + c] = f2b(acc[i][j][r] + bv);
        }
      } else {  // v -> transposed vT[(b*4+h)*256 + d][512]
        int h = c >> 8, d = c & 255;
#pragma unroll
        for (int i = 0; i < 4; ++i) {
          size_t row = m0 + wr * 64 + i * 16 + g * 4;
          int bb = (int)(row >> 9), ll = (int)(row & 511);
          size_t base = ((size_t)(bb * 4 + h) * 256 + d) * 512 + ll;
#pragma unroll
          for (int r = 0; r < 4; ++r)
            O2[base + r] = f2b(acc[i][j][r] + bv);
        }
      }
    }
  } else {
    const int bb = (int)(m0 >> 11);
#pragma unroll
    for (int i = 0; i < 4; ++i) {
      float rp[4] = {0.f, 0.f, 0.f, 0.f};
#pragma unroll
      for (int j = 0; j < 4; ++j) {
        int col = n0 + wc * 64 + j * 16 + lr;
        float wav = wa[col];
        float aqv = aq[bb * 1024 + col];
#pragma unroll
        for (int r = 0; r < 4; ++r)
          rp[r] += wav * fast_tanh(acc[i][j][r] + aqv);
      }
#pragma unroll
      for (int off = 1; off < 16; off <<= 1)
#pragma unroll
        for (int r = 0; r < 4; ++r)
          rp[r] += __shfl_xor(rp[r], off, 64);
      if (lr == 0) {
        size_t rowb = m0 + wr * 64 + i * 16 + g * 4;
#pragma unroll
        for (int r = 0; r < 4; ++r)
          atomicAdd(&sc[rowb + r], rp[r]);
      }
    }
  }
}

// ---------------- fused attention, QBLK=64 (round-15 proven) ----------------
__global__ __launch_bounds__(256, 2)
void attn_kernel(const unsigned short* __restrict__ q, const unsigned short* __restrict__ k,
                 const unsigned short* __restrict__ vT, const float* __restrict__ seq_mask,
                 unsigned short* __restrict__ ctx, float* __restrict__ attn_out)
{
  __shared__ char smem[68608];
  unsigned short* Qs = (unsigned short*)smem;           // [64][264]
  unsigned short* Ps = (unsigned short*)smem;           // [64][520]
  float* redm = (float*)(smem + 66560);
  float* reds = (float*)(smem + 67584);
  const int t = threadIdx.x, w = t >> 6, l = t & 63;
  const int lr = l & 15, g = l >> 4, lk8 = g * 8;
  const int wg = blockIdx.x;
  const int wgid = (wg & 7) * 128 + (wg >> 3);
  const int qt = wgid & 7, bh = wgid >> 3;
  const int h = bh & 3, b = bh >> 2;
  const int l0 = qt * 64;

  for (int idx = t; idx < 64 * 32; idx += 256) {
    int r = idx >> 5, ch = (idx & 31) * 8;
    *(sh8*)&Qs[r * 264 + ch] =
        *(const sh8*)&q[((size_t)(b * 512 + l0 + r)) * 1024 + h * 256 + ch];
  }
  __syncthreads();

  f32x4 accs[4][8] = {};
  const unsigned short* kbase = k + ((size_t)b * 512) * 1024 + h * 256;
#pragma unroll
  for (int ds = 0; ds < 8; ++ds) {
    int d0 = ds * 32;
    bf16x8 a[4];
#pragma unroll
    for (int i = 0; i < 4; ++i)
      a[i] = *(const bf16x8*)&Qs[(i * 16 + lr) * 264 + d0 + lk8];
#pragma unroll
    for (int j = 0; j < 8; ++j) {
      int kj = w * 128 + j * 16 + lr;
      bf16x8 bb = *(const bf16x8*)&kbase[(size_t)kj * 1024 + d0 + lk8];
#pragma unroll
      for (int i = 0; i < 4; ++i)
        accs[i][j] = mfma16(a[i], bb, accs[i][j]);
    }
  }

#pragma unroll
  for (int j = 0; j < 8; ++j) {
    int col = w * 128 + j * 16 + lr;
    float mv = seq_mask[b * 512 + col];
    bool msk = (mv == 0.f);
#pragma unroll
    for (int i = 0; i < 4; ++i)
#pragma unroll
      for (int r = 0; r < 4; ++r)
        accs[i][j][r] = msk ? NEGV : accs[i][j][r] * 0.0625f;
  }

  float mx[4][4], sm[4][4];
#pragma unroll
  for (int i = 0; i < 4; ++i)
#pragma unroll
    for (int r = 0; r < 4; ++r) {
      float m = accs[i][0][r];
#pragma unroll
      for (int j = 1; j < 8; ++j) m = fmaxf(m, accs[i][j][r]);
      mx[i][r] = m;
    }
#pragma unroll
  for (int off = 1; off < 16; off <<= 1)
#pragma unroll
    for (int i = 0; i < 4; ++i)
#pragma unroll
      for (int r = 0; r < 4; ++r)
        mx[i][r] = fmaxf(mx[i][r], __shfl_xor(mx[i][r], off, 64));
  if (lr == 0) {
#pragma unroll
    for (int i = 0; i < 4; ++i)
#pragma unroll
      for (int r = 0; r < 4; ++r)
        redm[w * 64 + i * 16 + g * 4 + r] = mx[i][r];
  }
  __syncthreads();
#pragma unroll
  for (int i = 0; i < 4; ++i)
#pragma unroll
    for (int r = 0; r < 4; ++r) {
      int row = i * 16 + g * 4 + r;
      mx[i][r] = fmaxf(fmaxf(redm[row], redm[64 + row]),
                       fmaxf(redm[128 + row], redm[192 + row]));
      sm[i][r] = 0.f;
    }

#pragma unroll
  for (int i = 0; i < 4; ++i)
#pragma unroll
    for (int j = 0; j < 8; ++j)
#pragma unroll
      for (int r = 0; r < 4; ++r) {
        float p = __expf(accs[i][j][r] - mx[i][r]);
        accs[i][j][r] = p;
        sm[i][r] += p;
      }
#pragma unroll
  for (int off = 1; off < 16; off <<= 1)
#pragma unroll
    for (int i = 0; i < 4; ++i)
#pragma unroll
      for (int r = 0; r < 4; ++r)
        sm[i][r] += __shfl_xor(sm[i][r], off, 64);
  if (lr == 0) {
#pragma unroll
    for (int i = 0; i < 4; ++i)
#pragma unroll
      for (int r = 0; r < 4; ++r)
        reds[w * 64 + i * 16 + g * 4 + r] = sm[i][r];
  }
  __syncthreads();
#pragma unroll
  for (int i = 0; i < 4; ++i)
#pragma unroll
    for (int r = 0; r < 4; ++r) {
      int row = i * 16 + g * 4 + r;
      float s = reds[row] + reds[64 + row] + reds[128 + row] + reds[192 + row];
      sm[i][r] = 1.f / s;
    }

#pragma unroll
  for (int i = 0; i < 4; ++i)
#pragma unroll
    for (int j = 0; j < 8; ++j) {
      int col = w * 128 + j * 16 + lr;
#pragma unroll
      for (int r = 0; r < 4; ++r) {
        int row = i * 16 + g * 4 + r;
        float pn = accs[i][j][r] * sm[i][r];
        Ps[row * 520 + col] = f2b(pn);
        if (h == 0)
          attn_out[((size_t)(b * 512 + l0 + row)) * 512 + col] = pn;
      }
    }
  __syncthreads();

  f32x4 acco[4][4] = {};
  const unsigned short* vbase = vT + ((size_t)(b * 4 + h)) * 256 * 512;
#pragma unroll
  for (int ks = 0; ks < 16; ++ks) {
    int kj0 = ks * 32;
    bf16x8 a[4];
#pragma unroll
    for (int i = 0; i < 4; ++i)
      a[i] = *(const bf16x8*)&Ps[(i * 16 + lr) * 520 + kj0 + lk8];
#pragma unroll
    for (int j = 0; j < 4; ++j) {
      int d = w * 64 + j * 16 + lr;
      bf16x8 bb = *(const bf16x8*)&vbase[(size_t)d * 512 + kj0 + lk8];
#pragma unroll
      for (int i = 0; i < 4; ++i)
        acco[i][j] = mfma16(a[i], bb, acco[i][j]);
    }
  }
#pragma unroll
  for (int i = 0; i < 4; ++i)
#pragma unroll
    for (int j = 0; j < 4; ++j) {
      int col = w * 64 + j * 16 + lr;
#pragma unroll
      for (int r = 0; r < 4; ++r) {
        int row = i * 16 + g * 4 + r;
        ctx[((size_t)(b * 512 + l0 + row)) * 1024 + h * 256 + col] = f2b(acco[i][j][r]);
      }
    }
}

// ---------------- LN + masked mean over L ----------------
__global__ __launch_bounds__(256)
void ln_mean(const unsigned short* __restrict__ sa, const float* __restrict__ g,
             const float* __restrict__ bt, const float* __restrict__ mask,
             float* __restrict__ poi_sum)
{
  const int b = blockIdx.y, ch = blockIdx.x;
  const int t = threadIdx.x, w = t >> 6, l = t & 63;
  float gg[16], bb[16];
#pragma unroll
  for (int j = 0; j < 16; ++j) { gg[j] = g[l * 16 + j]; bb[j] = bt[l * 16 + j]; }
  float accv[16];
#pragma unroll
  for (int j = 0; j < 16; ++j) accv[j] = 0.f;
  for (int rr = 0; rr < 16; ++rr) {
    int row = ch * 64 + w * 16 + rr;
    const unsigned short* rp = sa + ((size_t)(b * 512 + row)) * 1024 + l * 16;
    float x[16];
    sh8 v0 = *(const sh8*)rp;
    sh8 v1 = *(const sh8*)(rp + 8);
#pragma unroll
    for (int j = 0; j < 8; ++j) {
      x[j] = b2f((unsigned short)v0[j]);
      x[8 + j] = b2f((unsigned short)v1[j]);
    }
    float s = 0.f, s2 = 0.f;
#pragma unroll
    for (int j = 0; j < 16; ++j) { s += x[j]; s2 += x[j] * x[j]; }
#pragma unroll
    for (int off = 1; off < 64; off <<= 1) {
      s += __shfl_xor(s, off, 64);
      s2 += __shfl_xor(s2, off, 64);
    }
    float mean = s * (1.f / 1024.f);
    float var = s2 * (1.f / 1024.f) - mean * mean;
    float rinv = rsqrtf(var + 1e-5f);
    float mk = mask[b * 512 + row];
#pragma unroll
    for (int j = 0; j < 16; ++j) accv[j] += ((x[j] - mean) * rinv * gg[j] + bb[j]) * mk;
  }
#pragma unroll
  for (int j = 0; j < 16; ++j) atomicAdd(&poi_sum[b * 1024 + l * 16 + j], accv[j]);
}

// poi[b][n] = ps[b][n]/512;  aq[b][n] = (1/512) * sum_d ps[b][d] * wq[d][n]
__global__ __launch_bounds__(256)
void poi_gemv(const float* __restrict__ ps, const float* __restrict__ wq,
              float* __restrict__ poi, float* __restrict__ aq)
{
  const int b = blockIdx.y;
  const int n = blockIdx.x * 256 + threadIdx.x;
  const float* ib = ps + b * 1024;
  float acc = 0.f;
  for (int d = 0; d < 1024; d += 4) {
    acc += ib[d]     * wq[(size_t)d * 1024 + n]
         + ib[d + 1] * wq[(size_t)(d + 1) * 1024 + n]
         + ib[d + 2] * wq[(size_t)(d + 2) * 1024 + n]
         + ib[d + 3] * wq[(size_t)(d + 3) * 1024 + n];
  }
  poi[b * 1024 + n] = ib[n] * (1.f / 512.f);
  aq[b * 1024 + n] = acc * (1.f / 512.f);
}

// ---------------- fused his-softmax + weighted row-sum ----------------
__global__ __launch_bounds__(256)
void softhw(const float* __restrict__ sc, const float* __restrict__ mask,
            const unsigned short* __restrict__ his, float* __restrict__ hw)
{
  __shared__ float wloc[2048];
  __shared__ float red[4];
  const int b = blockIdx.y, kc = blockIdx.x;
  const int t = threadIdx.x, w = t >> 6, l = t & 63;
  float v[8];
  float mx = -3.0e38f;
#pragma unroll
  for (int i = 0; i < 8; ++i) {
    int kk = t + i * 256;
    float s = (mask[b * 2048 + kk] == 0.f) ? NEGV : sc[b * 2048 + kk];
    v[i] = s;
    mx = fmaxf(mx, s);
  }
#pragma unroll
  for (int off = 1; off < 64; off <<= 1) mx = fmaxf(mx, __shfl_xor(mx, off, 64));
  if (l == 0) red[w] = mx;
  __syncthreads();
  mx = fmaxf(fmaxf(red[0], red[1]), fmaxf(red[2], red[3]));
  float sum = 0.f;
#pragma unroll
  for (int i = 0; i < 8; ++i) {
    v[i] = __expf(v[i] - mx);
    wloc[t + i * 256] = v[i];
    sum += v[i];
  }
#pragma unroll
  for (int off = 1; off < 64; off <<= 1) sum += __shfl_xor(sum, off, 64);
  __syncthreads();
  if (l == 0) red[w] = sum;
  __syncthreads();
  sum = red[0] + red[1] + red[2] + red[3];
  const float inv = 1.f / sum;

  const int cb = t * 4;
  float a0 = 0.f, a1 = 0.f, a2 = 0.f, a3 = 0.f;
  for (int kk = 0; kk < 256; ++kk) {
    int k = kc * 256 + kk;
    float wg = wloc[k] * inv;
    sh4 vv = *(const sh4*)&his[((size_t)(b * 2048 + k)) * 1024 + cb];
    a0 += wg * b2f((unsigned short)vv[0]);
    a1 += wg * b2f((unsigned short)vv[1]);
    a2 += wg * b2f((unsigned short)vv[2]);
    a3 += wg * b2f((unsigned short)vv[3]);
  }
  atomicAdd(&hw[b * 1024 + cb + 0], a0);
  atomicAdd(&hw[b * 1024 + cb + 1], a1);
  atomicAdd(&hw[b * 1024 + cb + 2], a2);
  atomicAdd(&hw[b * 1024 + cb + 3], a3);
}

__global__ __launch_bounds__(256)
void gemv32(const float* __restrict__ in, const float* __restrict__ W, float* __restrict__ out)
{
  const int b = blockIdx.y;
  const int n = blockIdx.x * 256 + threadIdx.x;
  const float* ib = in + b * 1024;
  float acc = 0.f;
  for (int d = 0; d < 1024; d += 4) {
    acc += ib[d]     * W[(size_t)d * 1024 + n]
         + ib[d + 1] * W[(size_t)(d + 1) * 1024 + n]
         + ib[d + 2] * W[(size_t)(d + 2) * 1024 + n]
         + ib[d + 3] * W[(size_t)(d + 3) * 1024 + n];
  }
  out[b * 1024 + n] = acc;
}

__global__ __launch_bounds__(256)
void final_kernel(const float* __restrict__ aa_out, const float* __restrict__ g,
                  const float* __restrict__ bt, const float* __restrict__ poi,
                  float* __restrict__ out)
{
  __shared__ float r1[4], r2[4];
  const int b = blockIdx.x, t = threadIdx.x, w = t >> 6, l = t & 63;
  float x[4];
#pragma unroll
  for (int j = 0; j < 4; ++j) x[j] = aa_out[b * 1024 + t * 4 + j];
  float s = 0.f, s2 = 0.f;
#pragma unroll
  for (int j = 0; j < 4; ++j) { s += x[j]; s2 += x[j] * x[j]; }
#pragma unroll
  for (int off = 1; off < 64; off <<= 1) {
    s += __shfl_xor(s, off, 64);
    s2 += __shfl_xor(s2, off, 64);
  }
  if (l == 0) { r1[w] = s; r2[w] = s2; }
  __syncthreads();
  s = r1[0] + r1[1] + r1[2] + r1[3];
  s2 = r2[0] + r2[1] + r2[2] + r2[3];
  float mean = s * (1.f / 1024.f);
  float var = s2 * (1.f / 1024.f) - mean * mean;
  float rinv = rsqrtf(var + 1e-5f);
#pragma unroll
  for (int j = 0; j < 4; ++j) {
    int c = t * 4 + j;
    float lnv = (x[j] - mean) * rinv * g[c] + bt[c];
    float pv = poi[b * 1024 + c];
    out[b * 2048 + c] = pv;
    out[b * 2048 + 1024 + c] = pv + lnv;
  }
}

// ---------------- host launch ----------------
extern "C" void kernel_launch(void* const* d_in, const int* in_sizes, int n_in,
                              void* d_out, int out_size, void* d_ws, size_t ws_size,
                              hipStream_t stream)
{
  const float* seq_emb  = (const float*)d_in[0];
  const float* seq_mask = (const float*)d_in[1];
  const float* his_emb  = (const float*)d_in[2];
  const float* his_mask = (const float*)d_in[3];
  const float* sa_wq = (const float*)d_in[4];
  const float* sa_bq = (const float*)d_in[5];
  const float* sa_wk = (const float*)d_in[6];
  const float* sa_bk = (const float*)d_in[7];
  const float* sa_wv = (const float*)d_in[8];
  const float* sa_bv = (const float*)d_in[9];
  const float* sa_wo = (const float*)d_in[10];
  const float* sa_bo = (const float*)d_in[11];
  const float* sn_g  = (const float*)d_in[12];
  const float* sn_b  = (const float*)d_in[13];
  const float* aa_wq = (const float*)d_in[14];
  const float* aa_wk = (const float*)d_in[15];
  const float* aa_wv = (const float*)d_in[16];
  const float* aa_wo = (const float*)d_in[17];
  const float* aa_wa = (const float*)d_in[18];
  const float* ln_g  = (const float*)d_in[19];
  const float* ln_b  = (const float*)d_in[20];
  float* out = (float*)d_out;

  char* p = (char*)d_ws;
  size_t off = 0;
  auto alloc = [&](size_t bytes) -> void* {
    void* r = p + off;
    off += (bytes + 255) & ~(size_t)255;
    return r;
  };
  unsigned short* seqb = (unsigned short*)alloc((size_t)16384 * 1024 * 2);
  unsigned short* hisb = (unsigned short*)alloc((size_t)65536 * 1024 * 2);
  unsigned short* wcat = (unsigned short*)alloc((size_t)3072 * 1024 * 2);
  unsigned short* woT  = (unsigned short*)alloc((size_t)1024 * 1024 * 2);
  unsigned short* awkT = (unsigned short*)alloc((size_t)1024 * 1024 * 2);
  unsigned short* qb   = (unsigned short*)alloc((size_t)16384 * 1024 * 2);
  unsigned short* kb   = (unsigned short*)alloc((size_t)16384 * 1024 * 2);
  unsigned short* vTb  = (unsigned short*)alloc((size_t)16384 * 1024 * 2);
  unsigned short* ctxb = (unsigned short*)alloc((size_t)16384 * 1024 * 2);
  unsigned short* saob = (unsigned short*)alloc((size_t)16384 * 1024 * 2);
  float* poi_sum = (float*)alloc((size_t)32 * 1024 * 4);
  float* poi     = (float*)alloc((size_t)32 * 1024 * 4);
  float* aqb     = (float*)alloc((size_t)32 * 1024 * 4);
  float* ascore  = (float*)alloc((size_t)32 * 2048 * 4);
  float* hwb     = (float*)alloc((size_t)32 * 1024 * 4);
  float* actx    = (float*)alloc((size_t)32 * 1024 * 4);
  float* aaout   = (float*)alloc((size_t)32 * 1024 * 4);
  if (off > ws_size) return;

  hipMemsetAsync(poi_sum, 0, (size_t)(6 * 32 * 1024) * 4, stream);

  prep<<<3328, 256, 0, stream>>>(seq_emb, seqb, 16384 * 1024 / 4,
                                 his_emb, hisb, 65536 * 1024 / 4,
                                 sa_wq, sa_wk, sa_wv, sa_wo, aa_wk,
                                 wcat, wcat + (size_t)1024 * 1024,
                                 wcat + (size_t)2048 * 1024, woT, awkT);

  // fused QKV: M=16384, N=3072 -> 128 x 24 = 3072 blocks
  gemm128b64<1><<<3072, 256, 0, stream>>>(seqb, wcat, 24, sa_bq, sa_bk, sa_bv,
                                          qb, kb, vTb, nullptr, nullptr, nullptr);

  // attention: QBLK=64 -> 1024 blocks
  attn_kernel<<<1024, 256, 0, stream>>>(qb, kb, vTb, seq_mask, ctxb, out + 65536);

  // sa_out: M=16384, N=1024 -> 1024 blocks
  gemm128b64<0><<<1024, 256, 0, stream>>>(ctxb, woT, 8, sa_bo, nullptr, nullptr,
                                          saob, nullptr, nullptr, nullptr, nullptr, nullptr);
  ln_mean<<<dim3(8, 32), 256, 0, stream>>>(saob, sn_g, sn_b, seq_mask, poi_sum);
  poi_gemv<<<dim3(4, 32), 256, 0, stream>>>(poi_sum, aa_wq, poi, aqb);

  // his scores: M=65536, N=1024 -> 512 x 8 = 4096 blocks
  gemm128b64<2><<<4096, 256, 0, stream>>>(hisb, awkT, 8, nullptr, nullptr, nullptr,
                                          nullptr, nullptr, nullptr, aqb, aa_wa, ascore);
  softhw<<<dim3(8, 32), 256, 0, stream>>>(ascore, his_mask, hisb, hwb);
  gemv32<<<dim3(4, 32), 256, 0, stream>>>(hwb, aa_wv, actx);
  gemv32<<<dim3(4, 32), 256, 0, stream>>>(actx, aa_wo, aaout);
  final_kernel<<<32, 256, 0, stream>>>(aaout, ln_g, ln_b, poi, out);
}